// Round 9
// baseline (942.633 us; speedup 1.0000x reference)
//
#include <hip/hip_runtime.h>
#include <hip/hip_fp16.h>

#define N_NODES 100000
#define N_EDGES 600000
#define N_GRAPHS 5000
#define IN_DIM 11
#define HID 128
#define NREST 4
#define BN_EPS 1e-5f
#define SCAN_BS 256
#define NBLK ((N_NODES + SCAN_BS - 1) / SCAN_BS)   // 391
#define WSLOT 16384                                // ushorts per packed weight slot

typedef __bf16 bf16x8 __attribute__((ext_vector_type(8)));
typedef float f32x4 __attribute__((ext_vector_type(4)));

__device__ inline bf16x8 as_bf16x8(uint4 u) { return __builtin_bit_cast(bf16x8, u); }

// fp32 -> (hi, lo) truncated bf16 pair: x ~= hi + lo with |err| <= 2^-16 |x|
__device__ inline void split_bf16(float x, unsigned short& hi, unsigned short& lo) {
    unsigned int b = __float_as_uint(x);
    hi = (unsigned short)(b >> 16);
    float rem = x - __uint_as_float(b & 0xFFFF0000u);
    lo = (unsigned short)(__float_as_uint(rem) >> 16);
}

__device__ inline uint4 pack8(const unsigned short* h) {
    uint4 u;
    u.x = (unsigned)h[0] | ((unsigned)h[1] << 16);
    u.y = (unsigned)h[2] | ((unsigned)h[3] << 16);
    u.z = (unsigned)h[4] | ((unsigned)h[5] << 16);
    u.w = (unsigned)h[6] | ((unsigned)h[7] << 16);
    return u;
}

// ---------------- utility: zero the small control buffers ----------------
__global__ void k_zero(int* deg, int* gstart, int* gend, float* stats) {
    int i = blockIdx.x * 256 + threadIdx.x;
    if (i < N_NODES) deg[i] = 0;
    if (i < N_GRAPHS) { gstart[i] = 0; gend[i] = 0; }
    if (i < 5 * 2 * HID) stats[i] = 0.f;
}

// ---------------- CSR build (by dst) ----------------
__global__ void k_deg(const int* __restrict__ ei, int* __restrict__ deg) {
    int e = blockIdx.x * 256 + threadIdx.x;
    if (e < N_EDGES) atomicAdd(&deg[ei[N_EDGES + e]], 1);
}

__global__ void k_scan_a(const int* __restrict__ deg, int* __restrict__ rowstart,
                         int* __restrict__ bsum) {
    __shared__ int sh[SCAN_BS];
    int t = threadIdx.x, i = blockIdx.x * SCAN_BS + t;
    int v = (i < N_NODES) ? deg[i] : 0;
    sh[t] = v;
    __syncthreads();
    for (int off = 1; off < SCAN_BS; off <<= 1) {
        int add = (t >= off) ? sh[t - off] : 0;
        __syncthreads();
        sh[t] += add;
        __syncthreads();
    }
    if (i < N_NODES) rowstart[i] = sh[t] - v;
    if (t == SCAN_BS - 1) bsum[blockIdx.x] = sh[t];
}

__global__ void k_scan_b(const int* __restrict__ bsum, int* __restrict__ boff) {
    __shared__ int sh[512];
    int t = threadIdx.x;
    int v = (t < NBLK) ? bsum[t] : 0;
    sh[t] = v;
    __syncthreads();
    for (int off = 1; off < 512; off <<= 1) {
        int add = (t >= off) ? sh[t - off] : 0;
        __syncthreads();
        sh[t] += add;
        __syncthreads();
    }
    if (t < NBLK) boff[t] = sh[t] - v;
}

__global__ void k_scan_c(int* __restrict__ rowstart, const int* __restrict__ boff,
                         int* __restrict__ cur) {
    int i = blockIdx.x * 256 + threadIdx.x;
    if (i < N_NODES) {
        int v = rowstart[i] + boff[i / SCAN_BS];
        rowstart[i] = v;
        cur[i] = v;
    }
    if (i == 0) rowstart[N_NODES] = N_EDGES;
}

// packed edge record: {src, ea0, ea1, ea2} = 16 B, single dwordx4 per edge
__global__ void k_fill(const int* __restrict__ ei, const float* __restrict__ ea,
                       int* __restrict__ cur, uint4* __restrict__ csr_pack) {
    int e = blockIdx.x * 256 + threadIdx.x;
    if (e < N_EDGES) {
        int d = ei[N_EDGES + e];
        int p = atomicAdd(&cur[d], 1);
        uint4 pk;
        pk.x = (unsigned)ei[e];
        pk.y = __float_as_uint(ea[3 * e + 0]);
        pk.z = __float_as_uint(ea[3 * e + 1]);
        pk.w = __float_as_uint(ea[3 * e + 2]);
        csr_pack[p] = pk;
    }
}

// ---------------- weight pre-pack into MFMA B-fragment layout (hi/lo bf16) -------------
__global__ void k_pack(const float* __restrict__ w1_0, const float* __restrict__ w2_0,
                       const float* __restrict__ w1, const float* __restrict__ w2,
                       unsigned short* __restrict__ Whi, unsigned short* __restrict__ Wlo) {
    int bid = blockIdx.x;              // slot*32 + kc*8 + cb
    int slot = bid >> 5;
    int kc = (bid >> 3) & 3, cb = bid & 7;
    int lane = threadIdx.x;            // 64 threads
    const float* src;
    int K;
    if (slot == 0) { src = w1_0; K = IN_DIM; }
    else if (slot == 1) { src = w2_0; K = HID; }
    else if (slot < 6) { src = w1 + (size_t)(slot - 2) * HID * HID; K = HID; }
    else { src = w2 + (size_t)(slot - 6) * HID * HID; K = HID; }
    int col = cb * 16 + (lane & 15);
    int kbase = kc * 32 + 8 * (lane >> 4);
    unsigned short hi[8], lo[8];
#pragma unroll
    for (int j = 0; j < 8; ++j) {
        int k = kbase + j;
        float v = (k < K) ? src[(size_t)k * HID + col] : 0.f;
        split_bf16(v, hi[j], lo[j]);
    }
    size_t base = ((size_t)bid * 64 + lane) * 8;
    *(uint4*)(Whi + base) = pack8(hi);
    *(uint4*)(Wlo + base) = pack8(lo);
}

// ---------------- layer-0 aggregation (11 ch), 4 edge-slots/wave ----------
__global__ void k_agg0(const float* __restrict__ x, const int* __restrict__ rowstart,
                       const uint4* __restrict__ csr_pack,
                       const float* __restrict__ ew, const float* __restrict__ eb,
                       const float* __restrict__ epsp, float* __restrict__ Z0) {
    int wave = (blockIdx.x * blockDim.x + threadIdx.x) >> 6;
    int lane = threadIdx.x & 63;
    if (wave >= N_NODES) return;
    int n = wave;
    int slot = lane >> 4;            // 0..3
    int c = lane & 15;
    int cc = (c < IN_DIM) ? c : 0;
    float w0 = ew[cc], w1 = ew[IN_DIM + cc], w2 = ew[2 * IN_DIM + cc];
    float bb = eb[cc];
    float acc = 0.f;
    int i0 = rowstart[n], i1 = rowstart[n + 1];
    for (int i = i0 + slot; i < i1; i += 4) {
        uint4 pk = csr_pack[i];
        int s = (int)pk.x;
        float m = x[s * IN_DIM + cc] + __uint_as_float(pk.y) * w0 +
                  __uint_as_float(pk.z) * w1 + __uint_as_float(pk.w) * w2 + bb;
        acc += fmaxf(m, 0.f);
    }
    acc += __shfl_xor(acc, 16, 64);
    acc += __shfl_xor(acc, 32, 64);
    if (lane < IN_DIM) {
        float epsv = 1.0f + epsp[0];
        Z0[n * IN_DIM + lane] = epsv * x[n * IN_DIM + lane] + acc;
    }
}

// ---------------- layer 1..4 aggregation (128 ch): 4 slots, all-fp16 node state -------
__global__ __launch_bounds__(256, 4) void k_agg128(
        const __half* __restrict__ hh, const int* __restrict__ rowstart,
        const uint4* __restrict__ csr_pack,
        const float* __restrict__ ew, const float* __restrict__ eb,
        const float* __restrict__ epsp, int layer, float* __restrict__ Z) {
    int wave = (blockIdx.x * blockDim.x + threadIdx.x) >> 6;
    int lane = threadIdx.x & 63;
    if (wave >= N_NODES) return;
    int n = wave;
    int slot = lane >> 4;            // 0..3: edge slot
    int c = (lane & 15) * 8;         // 8 channels per lane
    float4 w0a = *(const float4*)(ew + 0 * HID + c), w0b = *(const float4*)(ew + 0 * HID + c + 4);
    float4 w1a = *(const float4*)(ew + 1 * HID + c), w1b = *(const float4*)(ew + 1 * HID + c + 4);
    float4 w2a = *(const float4*)(ew + 2 * HID + c), w2b = *(const float4*)(ew + 2 * HID + c + 4);
    float4 bba = *(const float4*)(eb + c),           bbb = *(const float4*)(eb + c + 4);
    float a0 = 0.f, a1 = 0.f, a2 = 0.f, a3 = 0.f, a4 = 0.f, a5 = 0.f, a6 = 0.f, a7 = 0.f;
    int i0 = rowstart[n], i1 = rowstart[n + 1];
    for (int i = i0 + slot; i < i1; i += 4) {
        uint4 pk = csr_pack[i];
        int s = (int)pk.x;
        float ea0 = __uint_as_float(pk.y);
        float ea1 = __uint_as_float(pk.z);
        float ea2 = __uint_as_float(pk.w);
        uint4 hv = *(const uint4*)(hh + (size_t)s * HID + c);    // 8 fp16 = 16 B
        float2 f0 = __half22float2(__builtin_bit_cast(__half2, hv.x));
        float2 f1 = __half22float2(__builtin_bit_cast(__half2, hv.y));
        float2 f2 = __half22float2(__builtin_bit_cast(__half2, hv.z));
        float2 f3 = __half22float2(__builtin_bit_cast(__half2, hv.w));
        a0 += fmaxf(f0.x + ea0 * w0a.x + ea1 * w1a.x + ea2 * w2a.x + bba.x, 0.f);
        a1 += fmaxf(f0.y + ea0 * w0a.y + ea1 * w1a.y + ea2 * w2a.y + bba.y, 0.f);
        a2 += fmaxf(f1.x + ea0 * w0a.z + ea1 * w1a.z + ea2 * w2a.z + bba.z, 0.f);
        a3 += fmaxf(f1.y + ea0 * w0a.w + ea1 * w1a.w + ea2 * w2a.w + bba.w, 0.f);
        a4 += fmaxf(f2.x + ea0 * w0b.x + ea1 * w1b.x + ea2 * w2b.x + bbb.x, 0.f);
        a5 += fmaxf(f2.y + ea0 * w0b.y + ea1 * w1b.y + ea2 * w2b.y + bbb.y, 0.f);
        a6 += fmaxf(f3.x + ea0 * w0b.z + ea1 * w1b.z + ea2 * w2b.z + bbb.z, 0.f);
        a7 += fmaxf(f3.y + ea0 * w0b.w + ea1 * w1b.w + ea2 * w2b.w + bbb.w, 0.f);
    }
    // reduce the 4 slots; xor 16/32 only mix lanes with identical channel set
#pragma unroll
    for (int m = 16; m <= 32; m <<= 1) {
        a0 += __shfl_xor(a0, m, 64); a1 += __shfl_xor(a1, m, 64);
        a2 += __shfl_xor(a2, m, 64); a3 += __shfl_xor(a3, m, 64);
        a4 += __shfl_xor(a4, m, 64); a5 += __shfl_xor(a5, m, 64);
        a6 += __shfl_xor(a6, m, 64); a7 += __shfl_xor(a7, m, 64);
    }
    if (slot == 0) {
        float epsv = 1.0f + epsp[layer];
        uint4 hv = *(const uint4*)(hh + (size_t)n * HID + c);    // own row (fp16)
        float2 f0 = __half22float2(__builtin_bit_cast(__half2, hv.x));
        float2 f1 = __half22float2(__builtin_bit_cast(__half2, hv.y));
        float2 f2 = __half22float2(__builtin_bit_cast(__half2, hv.z));
        float2 f3 = __half22float2(__builtin_bit_cast(__half2, hv.w));
        float4 za, zb;
        za.x = epsv * f0.x + a0; za.y = epsv * f0.y + a1;
        za.z = epsv * f1.x + a2; za.w = epsv * f1.y + a3;
        zb.x = epsv * f2.x + a4; zb.y = epsv * f2.y + a5;
        zb.z = epsv * f3.x + a6; zb.w = epsv * f3.y + a7;
        *(float4*)(Z + (size_t)n * HID + c) = za;
        *(float4*)(Z + (size_t)n * HID + c + 4) = zb;
    }
}

// ---------------- MFMA node MLP: Hpre = relu(Z@W1+b1)@W2+b2, + BN stats ----------------
// 64-row tile, 512 threads / 8 waves; wave w owns 16 output cols (cb = w).
// Per-wave: 48 MFMA/stage, acc = 4 f32x4 -> target <=64 VGPR for 8 waves/SIMD.
template <int K1>
__global__ __launch_bounds__(512, 8) void k_mlp(const float* Zin,
        const unsigned short* __restrict__ W1hi, const unsigned short* __restrict__ W1lo,
        const unsigned short* __restrict__ W2hi, const unsigned short* __restrict__ W2lo,
        const float* __restrict__ B1, const float* __restrict__ B2,
        float* Hpre, float* __restrict__ stats) {
    constexpr int KC1 = (K1 == 128) ? 4 : 1;
    __shared__ __align__(16) unsigned short ahi[4 * 4 * 64 * 8];   // 16 KB
    __shared__ __align__(16) unsigned short alo[4 * 4 * 64 * 8];   // 16 KB
    __shared__ float red[1024];                                    // 4 KB
    const int tid = threadIdx.x;
    const int w = tid >> 6;          // wave 0..7
    const int l = tid & 63;          // lane
    const int row0 = blockIdx.x * 64;

    // ---- stage Z -> packed A fragments (hi/lo bf16) ----
    if (K1 == 128) {
#pragma unroll
        for (int it = 0; it < 2; ++it) {
            int s = tid + it * 512;                 // s = ((wr*4+kc)*64+lane)
            int lane = s & 63, kc = (s >> 6) & 3, wr = s >> 8;
            int r = row0 + wr * 16 + (lane & 15);
            int k0 = kc * 32 + 8 * (lane >> 4);
            float v[8];
            if (r < N_NODES) {
                *(float4*)(v) = *(const float4*)(Zin + (size_t)r * 128 + k0);
                *(float4*)(v + 4) = *(const float4*)(Zin + (size_t)r * 128 + k0 + 4);
            } else {
#pragma unroll
                for (int j = 0; j < 8; ++j) v[j] = 0.f;
            }
            unsigned short h[8], q[8];
#pragma unroll
            for (int j = 0; j < 8; ++j) split_bf16(v[j], h[j], q[j]);
            *(uint4*)(ahi + (size_t)s * 8) = pack8(h);
            *(uint4*)(alo + (size_t)s * 8) = pack8(q);
        }
    } else {
        if (tid < 256) {
            int lane = tid & 63, wr = tid >> 6;
            int r = row0 + wr * 16 + (lane & 15);
            int k0 = 8 * (lane >> 4);
            float v[8];
#pragma unroll
            for (int j = 0; j < 8; ++j) {
                int k = k0 + j;
                v[j] = (r < N_NODES && k < IN_DIM) ? Zin[(size_t)r * IN_DIM + k] : 0.f;
            }
            unsigned short h[8], q[8];
#pragma unroll
            for (int j = 0; j < 8; ++j) split_bf16(v[j], h[j], q[j]);
            size_t s = (size_t)(wr * 4 + 0) * 64 + lane;
            *(uint4*)(ahi + s * 8) = pack8(h);
            *(uint4*)(alo + s * 8) = pack8(q);
        }
    }
    __syncthreads();

    const int cb = w;                // this wave's 16-col block
    const f32x4 zf = {0.f, 0.f, 0.f, 0.f};

    // ---- stage 1: T = relu(Z @ W1 + b1) ----
    f32x4 acc[4];
#pragma unroll
    for (int wr = 0; wr < 4; ++wr) acc[wr] = zf;

#pragma unroll
    for (int kc = 0; kc < KC1; ++kc) {
        bf16x8 bh = as_bf16x8(*(const uint4*)(W1hi + ((size_t)(kc * 8 + cb) * 64 + l) * 8));
        bf16x8 bl = as_bf16x8(*(const uint4*)(W1lo + ((size_t)(kc * 8 + cb) * 64 + l) * 8));
#pragma unroll
        for (int wr = 0; wr < 4; ++wr) {
            bf16x8 a_h = as_bf16x8(*(const uint4*)(ahi + ((size_t)(wr * 4 + kc) * 64 + l) * 8));
            bf16x8 a_l = as_bf16x8(*(const uint4*)(alo + ((size_t)(wr * 4 + kc) * 64 + l) * 8));
            acc[wr] = __builtin_amdgcn_mfma_f32_16x16x32_bf16(a_h, bh, acc[wr], 0, 0, 0);
            acc[wr] = __builtin_amdgcn_mfma_f32_16x16x32_bf16(a_l, bh, acc[wr], 0, 0, 0);
            acc[wr] = __builtin_amdgcn_mfma_f32_16x16x32_bf16(a_h, bl, acc[wr], 0, 0, 0);
        }
    }
    __syncthreads();   // all stage-1 A reads done; reuse ahi/alo for T

    // ---- bias+relu, repack T into stage-2 A-fragment layout ----
    // T col = cb*16 + (l&15); within kc2 = w>>1: koff = 16*(w&1) + (l&15)
    // -> lane l2 = g*16 + row_local, g = 2*(w&1) + ((l&15)>>3), elem j = (l&15)&7
    {
        float b1c = B1[cb * 16 + (l & 15)];
        int cc = l & 15;
        int g = 2 * (w & 1) + (cc >> 3);
        int j = cc & 7;
        int kc2 = w >> 1;
        int rl0 = (l >> 4) * 4;
#pragma unroll
        for (int wr = 0; wr < 4; ++wr) {
#pragma unroll
            for (int r = 0; r < 4; ++r) {
                float t = fmaxf(acc[wr][r] + b1c, 0.f);
                unsigned short th, tq;
                split_bf16(t, th, tq);
                int l2 = g * 16 + rl0 + r;
                int off = ((wr * 4 + kc2) * 64 + l2) * 8 + j;
                ahi[off] = th;
                alo[off] = tq;
            }
        }
    }
    __syncthreads();

    // ---- stage 2: out = T @ W2 + b2 ----
    f32x4 acc2[4];
#pragma unroll
    for (int wr = 0; wr < 4; ++wr) acc2[wr] = zf;

#pragma unroll
    for (int kc = 0; kc < 4; ++kc) {
        bf16x8 bh = as_bf16x8(*(const uint4*)(W2hi + ((size_t)(kc * 8 + cb) * 64 + l) * 8));
        bf16x8 bl = as_bf16x8(*(const uint4*)(W2lo + ((size_t)(kc * 8 + cb) * 64 + l) * 8));
#pragma unroll
        for (int wr = 0; wr < 4; ++wr) {
            bf16x8 a_h = as_bf16x8(*(const uint4*)(ahi + ((size_t)(wr * 4 + kc) * 64 + l) * 8));
            bf16x8 a_l = as_bf16x8(*(const uint4*)(alo + ((size_t)(wr * 4 + kc) * 64 + l) * 8));
            acc2[wr] = __builtin_amdgcn_mfma_f32_16x16x32_bf16(a_h, bh, acc2[wr], 0, 0, 0);
            acc2[wr] = __builtin_amdgcn_mfma_f32_16x16x32_bf16(a_l, bh, acc2[wr], 0, 0, 0);
            acc2[wr] = __builtin_amdgcn_mfma_f32_16x16x32_bf16(a_h, bl, acc2[wr], 0, 0, 0);
        }
    }

    // ---- epilogue: bias, store Hpre, BN partial stats ----
    {
        float b2c = B2[cb * 16 + (l & 15)];
        int col = cb * 16 + (l & 15);
        float s0 = 0.f, q0 = 0.f;
#pragma unroll
        for (int wr = 0; wr < 4; ++wr) {
#pragma unroll
            for (int r = 0; r < 4; ++r) {
                int grow = row0 + wr * 16 + (l >> 4) * 4 + r;
                if (grow < N_NODES) {
                    float o = acc2[wr][r] + b2c;
                    Hpre[(size_t)grow * 128 + col] = o;
                    s0 += o;
                    q0 += o * o;
                }
            }
        }
        red[w * 64 + l] = s0;
        red[512 + w * 64 + l] = q0;
    }
    __syncthreads();
    if (tid < 128) {
        // col = tid: w2 = tid>>4, c = tid&15; contributing lanes l = c + 16*g
        int b = (tid >> 4) * 64 + (tid & 15);
        float ss = red[b] + red[b + 16] + red[b + 32] + red[b + 48];
        float qq = red[512 + b] + red[512 + b + 16] + red[512 + b + 32] + red[512 + b + 48];
        atomicAdd(&stats[tid], ss);
        atomicAdd(&stats[128 + tid], qq);
    }
}

// ---------------- BN normalize + relu (+fp16 residual), writes fp16 h ----------------
__global__ void k_bn(const float* __restrict__ Hpre, const float* __restrict__ stats,
                     const float* __restrict__ gamma, const float* __restrict__ beta,
                     const __half* __restrict__ hprev, __half* __restrict__ hout) {
    int idx = blockIdx.x * 256 + threadIdx.x;   // 8-channel group index into [N,128]
    const float invN = 1.f / (float)N_NODES;
    int cg = (idx & 15) * 8;
    const float* hp = Hpre + (size_t)idx * 8;
    float4 v0 = *(const float4*)(hp);
    float4 v1 = *(const float4*)(hp + 4);
    float4 s0a = *(const float4*)(stats + cg);
    float4 s0b = *(const float4*)(stats + cg + 4);
    float4 s1a = *(const float4*)(stats + 128 + cg);
    float4 s1b = *(const float4*)(stats + 128 + cg + 4);
    float4 ga = *(const float4*)(gamma + cg);
    float4 gb = *(const float4*)(gamma + cg + 4);
    float4 ba = *(const float4*)(beta + cg);
    float4 bb = *(const float4*)(beta + cg + 4);
    float vv[8] = {v0.x, v0.y, v0.z, v0.w, v1.x, v1.y, v1.z, v1.w};
    float sm[8] = {s0a.x, s0a.y, s0a.z, s0a.w, s0b.x, s0b.y, s0b.z, s0b.w};
    float sq[8] = {s1a.x, s1a.y, s1a.z, s1a.w, s1b.x, s1b.y, s1b.z, s1b.w};
    float gg[8] = {ga.x, ga.y, ga.z, ga.w, gb.x, gb.y, gb.z, gb.w};
    float be[8] = {ba.x, ba.y, ba.z, ba.w, bb.x, bb.y, bb.z, bb.w};
    float o[8];
#pragma unroll
    for (int j = 0; j < 8; ++j) {
        float mu = sm[j] * invN, var = sq[j] * invN - mu * mu;
        o[j] = fmaxf((vv[j] - mu) * rsqrtf(var + BN_EPS) * gg[j] + be[j], 0.f);
    }
    if (hprev) {
        uint4 pv = *(const uint4*)(hprev + (size_t)idx * 8);
        float2 r0 = __half22float2(__builtin_bit_cast(__half2, pv.x));
        float2 r1 = __half22float2(__builtin_bit_cast(__half2, pv.y));
        float2 r2 = __half22float2(__builtin_bit_cast(__half2, pv.z));
        float2 r3 = __half22float2(__builtin_bit_cast(__half2, pv.w));
        o[0] += r0.x; o[1] += r0.y; o[2] += r1.x; o[3] += r1.y;
        o[4] += r2.x; o[5] += r2.y; o[6] += r3.x; o[7] += r3.y;
    }
    uint4 st;
    st.x = __builtin_bit_cast(unsigned int, __floats2half2_rn(o[0], o[1]));
    st.y = __builtin_bit_cast(unsigned int, __floats2half2_rn(o[2], o[3]));
    st.z = __builtin_bit_cast(unsigned int, __floats2half2_rn(o[4], o[5]));
    st.w = __builtin_bit_cast(unsigned int, __floats2half2_rn(o[6], o[7]));
    *(uint4*)(hout + (size_t)idx * 8) = st;
}

// ---------------- graph boundaries (batch is sorted) ----------------
__global__ void k_bounds(const int* __restrict__ batch, int* __restrict__ gstart,
                         int* __restrict__ gend) {
    int r = blockIdx.x * 256 + threadIdx.x;
    if (r >= N_NODES) return;
    int b = batch[r];
    if (r == 0 || batch[r - 1] != b) gstart[b] = r;
    if (r == N_NODES - 1 || batch[r + 1] != b) gend[b] = r + 1;
}

// ---------------- mean pool per graph (wave per graph, fp16 input) ----------------
__global__ void k_pool(const __half* __restrict__ hh, const int* __restrict__ gstart,
                       const int* __restrict__ gend, float* __restrict__ pooled) {
    int wave = (blockIdx.x * blockDim.x + threadIdx.x) >> 6;
    int lane = threadIdx.x & 63;
    if (wave >= N_GRAPHS) return;
    int g = wave;
    int c = lane * 2;
    int a = gstart[g], b = gend[g];
    float ax = 0.f, ay = 0.f;
    for (int r = a; r < b; ++r) {
        __half2 v = *(const __half2*)(hh + (size_t)r * HID + c);
        float2 f = __half22float2(v);
        ax += f.x;
        ay += f.y;
    }
    float d = fmaxf((float)(b - a), 1.f);
    float2 o;
    o.x = ax / d;
    o.y = ay / d;
    *(float2*)(pooled + (size_t)g * HID + c) = o;
}

// ---------------- head MLP ----------------
__global__ void k_head(const float* __restrict__ pooled, const float* __restrict__ hw1,
                       const float* __restrict__ hb1, const float* __restrict__ hw2,
                       const float* __restrict__ hb2, const float* __restrict__ hw3,
                       const float* __restrict__ hb3, float* __restrict__ out) {
    __shared__ float ps[2][128];
    __shared__ float t1s[2][128];
    __shared__ float red[256];
    int tid = threadIdx.x;
    int rr = tid >> 7, c = tid & 127;
    int row = blockIdx.x * 2 + rr;
    ps[rr][c] = pooled[(size_t)row * 128 + c];
    __syncthreads();
    float a = hb1[c];
    for (int k = 0; k < 128; ++k) a = fmaf(ps[rr][k], hw1[k * 128 + c], a);
    t1s[rr][c] = fmaxf(a, 0.f);
    __syncthreads();
    float b = hb2[c];
    for (int k = 0; k < 128; ++k) b = fmaf(t1s[rr][k], hw2[k * 128 + c], b);
    b = fmaxf(b, 0.f);
    red[tid] = b * hw3[c];
    for (int s = 64; s > 0; s >>= 1) {
        __syncthreads();
        if (c < s) red[tid] += red[tid + s];
    }
    __syncthreads();
    if (c == 0) out[row] = red[tid] + hb3[0];
}

// ---------------- launch ----------------
extern "C" void kernel_launch(void* const* d_in, const int* in_sizes, int n_in,
                              void* d_out, int out_size, void* d_ws, size_t ws_size,
                              hipStream_t stream) {
    const float* x = (const float*)d_in[0];
    const float* edge_attr = (const float*)d_in[1];
    const float* e_w0 = (const float*)d_in[2];
    const float* e_b0 = (const float*)d_in[3];
    const float* w1_0 = (const float*)d_in[4];
    const float* b1_0 = (const float*)d_in[5];
    const float* w2_0 = (const float*)d_in[6];
    const float* b2_0 = (const float*)d_in[7];
    const float* gamma0 = (const float*)d_in[8];
    const float* beta0 = (const float*)d_in[9];
    const float* eps0 = (const float*)d_in[10];
    const float* e_w = (const float*)d_in[11];
    const float* e_b = (const float*)d_in[12];
    const float* w1 = (const float*)d_in[13];
    const float* b1 = (const float*)d_in[14];
    const float* w2 = (const float*)d_in[15];
    const float* b2 = (const float*)d_in[16];
    const float* gamma = (const float*)d_in[17];
    const float* beta = (const float*)d_in[18];
    const float* eps_r = (const float*)d_in[19];
    const float* hw1 = (const float*)d_in[20];
    const float* hb1 = (const float*)d_in[21];
    const float* hw2 = (const float*)d_in[22];
    const float* hb2 = (const float*)d_in[23];
    const float* hw3 = (const float*)d_in[24];
    const float* hb3 = (const float*)d_in[25];
    const int* edge_index = (const int*)d_in[26];
    const int* batch = (const int*)d_in[27];
    float* out = (float*)d_out;

    // workspace layout (all offsets in floats, %4==0 -> 16B aligned)
    float* wsf = (float*)d_ws;
    size_t off = 0;
    float* ZB = wsf + off;     off += (size_t)N_NODES * HID;       // Z / Hpre (aliased)
    float* Z0 = wsf + off;     off += (size_t)N_NODES * IN_DIM + 4;
    float* pooled = wsf + off; off += (size_t)N_GRAPHS * HID;
    float* stats = wsf + off;  off += 5 * 2 * HID;
    __half* hhA = (__half*)(wsf + off); off += (size_t)N_NODES * HID / 2;  // fp16 h (buf A)
    __half* hhB = (__half*)(wsf + off); off += (size_t)N_NODES * HID / 2;  // fp16 h (buf B)
    int* ib = (int*)(wsf + off);
    uint4* csr_pack = (uint4*)ib;                 // 16B-aligned
    size_t io = 4 * (size_t)N_EDGES;
    int* deg = ib + io;      io += N_NODES;
    int* rowstart = ib + io; io += N_NODES + 4;
    int* cur = ib + io;      io += N_NODES;
    int* gstart = ib + io;   io += N_GRAPHS;
    int* gend = ib + io;     io += N_GRAPHS;
    int* bsum = ib + io;     io += 512;
    int* boff = ib + io;     io += 512;
    unsigned short* Whi = (unsigned short*)(ib + io);          // 10 slots * 16384 ushorts
    unsigned short* Wlo = Whi + 10 * WSLOT;

    const int EB = (N_EDGES + 255) / 256;        // 2344
    const int NB = (N_NODES + 255) / 256;        // 391
    const int MLPB = (N_NODES + 63) / 64;        // 1563
    const int BNB = (N_NODES * HID / 8) / 256;   // 6250

    // zero control buffers + pack weights (ws is poisoned before every call)
    k_zero<<<NB, 256, 0, stream>>>(deg, gstart, gend, stats);
    k_pack<<<320, 64, 0, stream>>>(w1_0, w2_0, w1, w2, Whi, Wlo);

    // CSR build
    k_deg<<<EB, 256, 0, stream>>>(edge_index, deg);
    k_scan_a<<<NBLK, SCAN_BS, 0, stream>>>(deg, rowstart, bsum);
    k_scan_b<<<1, 512, 0, stream>>>(bsum, boff);
    k_scan_c<<<NB, 256, 0, stream>>>(rowstart, boff, cur);
    k_fill<<<EB, 256, 0, stream>>>(edge_index, edge_attr, cur, csr_pack);

    // layer 0
    k_agg0<<<(N_NODES * 64) / 256, 256, 0, stream>>>(x, rowstart, csr_pack, e_w0,
                                                     e_b0, eps0, Z0);
    k_mlp<IN_DIM><<<MLPB, 512, 0, stream>>>(Z0, Whi + 0 * WSLOT, Wlo + 0 * WSLOT,
                                            Whi + 1 * WSLOT, Wlo + 1 * WSLOT,
                                            b1_0, b2_0, ZB, stats);
    k_bn<<<BNB, 256, 0, stream>>>(ZB, stats, gamma0, beta0, (const __half*)nullptr, hhA);

    // layers 1..4 (fp16 node state, double-buffered)
    __half* hcur = hhA;
    __half* hnxt = hhB;
    for (int i = 0; i < NREST; ++i) {
        k_agg128<<<(N_NODES * 64) / 256, 256, 0, stream>>>(
            hcur, rowstart, csr_pack, e_w + (size_t)i * 3 * HID,
            e_b + (size_t)i * HID, eps_r, i, ZB);
        k_mlp<HID><<<MLPB, 512, 0, stream>>>(ZB, Whi + (size_t)(2 + i) * WSLOT,
                                             Wlo + (size_t)(2 + i) * WSLOT,
                                             Whi + (size_t)(6 + i) * WSLOT,
                                             Wlo + (size_t)(6 + i) * WSLOT,
                                             b1 + (size_t)i * HID, b2 + (size_t)i * HID,
                                             ZB, stats + (size_t)(i + 1) * 2 * HID);
        k_bn<<<BNB, 256, 0, stream>>>(ZB, stats + (size_t)(i + 1) * 2 * HID,
                                      gamma + (size_t)i * HID, beta + (size_t)i * HID,
                                      hcur, hnxt);
        __half* t = hcur; hcur = hnxt; hnxt = t;
    }

    // pooling + head
    k_bounds<<<NB, 256, 0, stream>>>(batch, gstart, gend);
    k_pool<<<(N_GRAPHS * 64) / 256, 256, 0, stream>>>(hcur, gstart, gend, pooled);
    k_head<<<N_GRAPHS / 2, 256, 0, stream>>>(pooled, hw1, hb1, hw2, hb2, hw3, hb3, out);
}

// Round 11
// 847.843 us; speedup vs baseline: 1.1118x; 1.1118x over previous
//
#include <hip/hip_runtime.h>
#include <hip/hip_fp16.h>

#define N_NODES 100000
#define N_EDGES 600000
#define N_GRAPHS 5000
#define IN_DIM 11
#define HID 128
#define NREST 4
#define BN_EPS 1e-5f
#define SCAN_BS 256
#define NBLK ((N_NODES + SCAN_BS - 1) / SCAN_BS)   // 391
#define WSLOT 16384                                // ushorts per packed weight slot
#define FB ((N_NODES + 63) / 64)                   // 1563 fused blocks

typedef __bf16 bf16x8 __attribute__((ext_vector_type(8)));
typedef float f32x4 __attribute__((ext_vector_type(4)));

__device__ inline bf16x8 as_bf16x8(uint4 u) { return __builtin_bit_cast(bf16x8, u); }

// fp32 -> (hi, lo) truncated bf16 pair: x ~= hi + lo with |err| <= 2^-16 |x|
__device__ inline void split_bf16(float x, unsigned short& hi, unsigned short& lo) {
    unsigned int b = __float_as_uint(x);
    hi = (unsigned short)(b >> 16);
    float rem = x - __uint_as_float(b & 0xFFFF0000u);
    lo = (unsigned short)(__float_as_uint(rem) >> 16);
}

__device__ inline uint4 pack8(const unsigned short* h) {
    uint4 u;
    u.x = (unsigned)h[0] | ((unsigned)h[1] << 16);
    u.y = (unsigned)h[2] | ((unsigned)h[3] << 16);
    u.z = (unsigned)h[4] | ((unsigned)h[5] << 16);
    u.w = (unsigned)h[6] | ((unsigned)h[7] << 16);
    return u;
}

// ---------------- utility: zero the small control buffers ----------------
__global__ void k_zero(int* deg, int* gstart, int* gend, float* stats) {
    int i = blockIdx.x * 256 + threadIdx.x;
    if (i < N_NODES) deg[i] = 0;
    if (i < N_GRAPHS) { gstart[i] = 0; gend[i] = 0; }
    if (i < 5 * 2 * HID) stats[i] = 0.f;
}

// ---------------- CSR build (by dst) ----------------
__global__ void k_deg(const int* __restrict__ ei, int* __restrict__ deg) {
    int e = blockIdx.x * 256 + threadIdx.x;
    if (e < N_EDGES) atomicAdd(&deg[ei[N_EDGES + e]], 1);
}

__global__ void k_scan_a(const int* __restrict__ deg, int* __restrict__ rowstart,
                         int* __restrict__ bsum) {
    __shared__ int sh[SCAN_BS];
    int t = threadIdx.x, i = blockIdx.x * SCAN_BS + t;
    int v = (i < N_NODES) ? deg[i] : 0;
    sh[t] = v;
    __syncthreads();
    for (int off = 1; off < SCAN_BS; off <<= 1) {
        int add = (t >= off) ? sh[t - off] : 0;
        __syncthreads();
        sh[t] += add;
        __syncthreads();
    }
    if (i < N_NODES) rowstart[i] = sh[t] - v;
    if (t == SCAN_BS - 1) bsum[blockIdx.x] = sh[t];
}

__global__ void k_scan_b(const int* __restrict__ bsum, int* __restrict__ boff) {
    __shared__ int sh[512];
    int t = threadIdx.x;
    int v = (t < NBLK) ? bsum[t] : 0;
    sh[t] = v;
    __syncthreads();
    for (int off = 1; off < 512; off <<= 1) {
        int add = (t >= off) ? sh[t - off] : 0;
        __syncthreads();
        sh[t] += add;
        __syncthreads();
    }
    if (t < NBLK) boff[t] = sh[t] - v;
}

__global__ void k_scan_c(int* __restrict__ rowstart, const int* __restrict__ boff,
                         int* __restrict__ cur) {
    int i = blockIdx.x * 256 + threadIdx.x;
    if (i < N_NODES) {
        int v = rowstart[i] + boff[i / SCAN_BS];
        rowstart[i] = v;
        cur[i] = v;
    }
    if (i == 0) rowstart[N_NODES] = N_EDGES;
}

// packed edge record: {src, ea0, ea1, ea2} = 16 B, single dwordx4 per edge
__global__ void k_fill(const int* __restrict__ ei, const float* __restrict__ ea,
                       int* __restrict__ cur, uint4* __restrict__ csr_pack) {
    int e = blockIdx.x * 256 + threadIdx.x;
    if (e < N_EDGES) {
        int d = ei[N_EDGES + e];
        int p = atomicAdd(&cur[d], 1);
        uint4 pk;
        pk.x = (unsigned)ei[e];
        pk.y = __float_as_uint(ea[3 * e + 0]);
        pk.z = __float_as_uint(ea[3 * e + 1]);
        pk.w = __float_as_uint(ea[3 * e + 2]);
        csr_pack[p] = pk;
    }
}

// ---------------- weight pre-pack into MFMA B-fragment layout (hi/lo bf16) -------------
__global__ void k_pack(const float* __restrict__ w1_0, const float* __restrict__ w2_0,
                       const float* __restrict__ w1, const float* __restrict__ w2,
                       unsigned short* __restrict__ Whi, unsigned short* __restrict__ Wlo) {
    int bid = blockIdx.x;              // slot*32 + kc*8 + cb
    int slot = bid >> 5;
    int kc = (bid >> 3) & 3, cb = bid & 7;
    int lane = threadIdx.x;            // 64 threads
    const float* src;
    int K;
    if (slot == 0) { src = w1_0; K = IN_DIM; }
    else if (slot == 1) { src = w2_0; K = HID; }
    else if (slot < 6) { src = w1 + (size_t)(slot - 2) * HID * HID; K = HID; }
    else { src = w2 + (size_t)(slot - 6) * HID * HID; K = HID; }
    int col = cb * 16 + (lane & 15);
    int kbase = kc * 32 + 8 * (lane >> 4);
    unsigned short hi[8], lo[8];
#pragma unroll
    for (int j = 0; j < 8; ++j) {
        int k = kbase + j;
        float v = (k < K) ? src[(size_t)k * HID + col] : 0.f;
        split_bf16(v, hi[j], lo[j]);
    }
    size_t base = ((size_t)bid * 64 + lane) * 8;
    *(uint4*)(Whi + base) = pack8(hi);
    *(uint4*)(Wlo + base) = pack8(lo);
}

// ---------------- FUSED layer: gather-aggregate -> LDS fragments -> 2-stage MFMA MLP --
// 64-row tile, 512 threads / 8 waves. Wave w gathers nodes w*8..w*8+7 (4 edge-slots),
// writes Z directly into LDS as bf16 hi/lo A-fragments (no global Z round-trip).
// Then the verified round-9 MFMA stages; epilogue re-staged through LDS for
// fully-coalesced Hpre row stores. stats = per-layer BN sums (atomic).
template <int K1>
__global__ __launch_bounds__(512, 4) void k_fused(
        const float* __restrict__ x, const __half* __restrict__ hh,
        const int* __restrict__ rowstart, const uint4* __restrict__ csr_pack,
        const float* __restrict__ ew, const float* __restrict__ eb,
        const float* __restrict__ epsp, int layer,
        const unsigned short* __restrict__ W1hi, const unsigned short* __restrict__ W1lo,
        const unsigned short* __restrict__ W2hi, const unsigned short* __restrict__ W2lo,
        const float* __restrict__ B1, const float* __restrict__ B2,
        float* __restrict__ Hpre, float* __restrict__ stats) {
    constexpr int KC1 = (K1 == 128) ? 4 : 1;
    __shared__ __align__(16) unsigned short afrag[2 * 4 * 4 * 64 * 8];  // 32 KB (ahi|alo)
    __shared__ float red[1024];                                         // 4 KB
    unsigned short* ahi = afrag;
    unsigned short* alo = afrag + 8192;
    const int tid = threadIdx.x;
    const int w = tid >> 6;          // wave 0..7
    const int l = tid & 63;          // lane
    const int row0 = blockIdx.x * 64;
    const float epsv = 1.0f + epsp[layer];
    const int slot = l >> 4;         // 0..3 edge slot

    if (K1 == 11) {
        // pre-zero the kc=0 fragment region (the only one stage 1 reads)
        if (tid < 256) {
            int off = ((tid >> 6) * 256 + (tid & 63)) * 8;
            uint4 z = {0, 0, 0, 0};
            *(uint4*)(ahi + off) = z;
            *(uint4*)(alo + off) = z;
        }
        __syncthreads();
    }

    // ---- gather phase: aggregate + write A-fragments ----
    if (K1 == 128) {
        int cg = (l & 15) * 8;       // 8 channels per lane
        float4 w0a = *(const float4*)(ew + 0 * HID + cg), w0b = *(const float4*)(ew + 0 * HID + cg + 4);
        float4 w1a = *(const float4*)(ew + 1 * HID + cg), w1b = *(const float4*)(ew + 1 * HID + cg + 4);
        float4 w2a = *(const float4*)(ew + 2 * HID + cg), w2b = *(const float4*)(ew + 2 * HID + cg + 4);
        float4 bba = *(const float4*)(eb + cg),           bbb = *(const float4*)(eb + cg + 4);
        for (int nn = 0; nn < 8; ++nn) {
            int rl = w * 8 + nn;
            int n = row0 + rl;
            bool valid = (n < N_NODES);
            float a0 = 0.f, a1 = 0.f, a2 = 0.f, a3 = 0.f, a4 = 0.f, a5 = 0.f, a6 = 0.f, a7 = 0.f;
            if (valid) {
                int i0 = rowstart[n], i1 = rowstart[n + 1];
                for (int i = i0 + slot; i < i1; i += 4) {
                    uint4 pk = csr_pack[i];
                    int s = (int)pk.x;
                    float ea0 = __uint_as_float(pk.y);
                    float ea1 = __uint_as_float(pk.z);
                    float ea2 = __uint_as_float(pk.w);
                    uint4 hv = *(const uint4*)(hh + (size_t)s * HID + cg);
                    float2 f0 = __half22float2(__builtin_bit_cast(__half2, hv.x));
                    float2 f1 = __half22float2(__builtin_bit_cast(__half2, hv.y));
                    float2 f2 = __half22float2(__builtin_bit_cast(__half2, hv.z));
                    float2 f3 = __half22float2(__builtin_bit_cast(__half2, hv.w));
                    a0 += fmaxf(f0.x + ea0 * w0a.x + ea1 * w1a.x + ea2 * w2a.x + bba.x, 0.f);
                    a1 += fmaxf(f0.y + ea0 * w0a.y + ea1 * w1a.y + ea2 * w2a.y + bba.y, 0.f);
                    a2 += fmaxf(f1.x + ea0 * w0a.z + ea1 * w1a.z + ea2 * w2a.z + bba.z, 0.f);
                    a3 += fmaxf(f1.y + ea0 * w0a.w + ea1 * w1a.w + ea2 * w2a.w + bba.w, 0.f);
                    a4 += fmaxf(f2.x + ea0 * w0b.x + ea1 * w1b.x + ea2 * w2b.x + bbb.x, 0.f);
                    a5 += fmaxf(f2.y + ea0 * w0b.y + ea1 * w1b.y + ea2 * w2b.y + bbb.y, 0.f);
                    a6 += fmaxf(f3.x + ea0 * w0b.z + ea1 * w1b.z + ea2 * w2b.z + bbb.z, 0.f);
                    a7 += fmaxf(f3.y + ea0 * w0b.w + ea1 * w1b.w + ea2 * w2b.w + bbb.w, 0.f);
                }
            }
#pragma unroll
            for (int m = 16; m <= 32; m <<= 1) {
                a0 += __shfl_xor(a0, m, 64); a1 += __shfl_xor(a1, m, 64);
                a2 += __shfl_xor(a2, m, 64); a3 += __shfl_xor(a3, m, 64);
                a4 += __shfl_xor(a4, m, 64); a5 += __shfl_xor(a5, m, 64);
                a6 += __shfl_xor(a6, m, 64); a7 += __shfl_xor(a7, m, 64);
            }
            if (slot == 0) {       // lanes 0..15 own the reduced row
                int lc = l & 15;
                float z[8] = {0.f, 0.f, 0.f, 0.f, 0.f, 0.f, 0.f, 0.f};
                if (valid) {
                    uint4 hv = *(const uint4*)(hh + (size_t)n * HID + cg);
                    float2 f0 = __half22float2(__builtin_bit_cast(__half2, hv.x));
                    float2 f1 = __half22float2(__builtin_bit_cast(__half2, hv.y));
                    float2 f2 = __half22float2(__builtin_bit_cast(__half2, hv.z));
                    float2 f3 = __half22float2(__builtin_bit_cast(__half2, hv.w));
                    z[0] = epsv * f0.x + a0; z[1] = epsv * f0.y + a1;
                    z[2] = epsv * f1.x + a2; z[3] = epsv * f1.y + a3;
                    z[4] = epsv * f2.x + a4; z[5] = epsv * f2.y + a5;
                    z[6] = epsv * f3.x + a6; z[7] = epsv * f3.y + a7;
                }
                unsigned short h8[8], q8[8];
#pragma unroll
                for (int j = 0; j < 8; ++j) split_bf16(z[j], h8[j], q8[j]);
                int sidx = ((rl >> 4) * 4 + (lc >> 2)) * 64 + (lc & 3) * 16 + (rl & 15);
                *(uint4*)(ahi + (size_t)sidx * 8) = pack8(h8);
                *(uint4*)(alo + (size_t)sidx * 8) = pack8(q8);
            }
        }
    } else {
        // K1 == 11: lane = slot*16 + c, scalar channel
        int c = l & 15;
        int cc = (c < IN_DIM) ? c : 0;
        float w0 = ew[cc], w1 = ew[IN_DIM + cc], w2 = ew[2 * IN_DIM + cc];
        float bb = eb[cc];
        for (int nn = 0; nn < 8; ++nn) {
            int rl = w * 8 + nn;
            int n = row0 + rl;
            bool valid = (n < N_NODES);
            float acc = 0.f;
            if (valid) {
                int i0 = rowstart[n], i1 = rowstart[n + 1];
                for (int i = i0 + slot; i < i1; i += 4) {
                    uint4 pk = csr_pack[i];
                    int s = (int)pk.x;
                    float m = x[s * IN_DIM + cc] + __uint_as_float(pk.y) * w0 +
                              __uint_as_float(pk.z) * w1 + __uint_as_float(pk.w) * w2 + bb;
                    acc += fmaxf(m, 0.f);
                }
            }
            acc += __shfl_xor(acc, 16, 64);
            acc += __shfl_xor(acc, 32, 64);
            if (slot == 0 && c < IN_DIM && valid) {
                float z = epsv * x[n * IN_DIM + c] + acc;
                unsigned short zh, zq;
                split_bf16(z, zh, zq);
                int sidx = ((rl >> 4) * 4 + 0) * 64 + (c >> 3) * 16 + (rl & 15);
                int off = sidx * 8 + (c & 7);
                ahi[off] = zh;
                alo[off] = zq;
            }
        }
    }
    __syncthreads();

    const int cb = w;                // this wave's 16-col block
    const f32x4 zf = {0.f, 0.f, 0.f, 0.f};

    // ---- stage 1: T = relu(Z @ W1 + b1) ----
    f32x4 acc[4];
#pragma unroll
    for (int wr = 0; wr < 4; ++wr) acc[wr] = zf;

#pragma unroll
    for (int kc = 0; kc < KC1; ++kc) {
        bf16x8 bh = as_bf16x8(*(const uint4*)(W1hi + ((size_t)(kc * 8 + cb) * 64 + l) * 8));
        bf16x8 bl = as_bf16x8(*(const uint4*)(W1lo + ((size_t)(kc * 8 + cb) * 64 + l) * 8));
#pragma unroll
        for (int wr = 0; wr < 4; ++wr) {
            bf16x8 a_h = as_bf16x8(*(const uint4*)(ahi + ((size_t)(wr * 4 + kc) * 64 + l) * 8));
            bf16x8 a_l = as_bf16x8(*(const uint4*)(alo + ((size_t)(wr * 4 + kc) * 64 + l) * 8));
            acc[wr] = __builtin_amdgcn_mfma_f32_16x16x32_bf16(a_h, bh, acc[wr], 0, 0, 0);
            acc[wr] = __builtin_amdgcn_mfma_f32_16x16x32_bf16(a_l, bh, acc[wr], 0, 0, 0);
            acc[wr] = __builtin_amdgcn_mfma_f32_16x16x32_bf16(a_h, bl, acc[wr], 0, 0, 0);
        }
    }
    __syncthreads();   // all stage-1 A reads done; reuse ahi/alo for T

    // ---- bias+relu, repack T into stage-2 A-fragment layout (round-9 verified) ----
    {
        float b1c = B1[cb * 16 + (l & 15)];
        int cc = l & 15;
        int g = 2 * (w & 1) + (cc >> 3);
        int j = cc & 7;
        int kc2 = w >> 1;
        int rl0 = (l >> 4) * 4;
#pragma unroll
        for (int wr = 0; wr < 4; ++wr) {
#pragma unroll
            for (int r = 0; r < 4; ++r) {
                float t = fmaxf(acc[wr][r] + b1c, 0.f);
                unsigned short th, tq;
                split_bf16(t, th, tq);
                int l2 = g * 16 + rl0 + r;
                int off = ((wr * 4 + kc2) * 64 + l2) * 8 + j;
                ahi[off] = th;
                alo[off] = tq;
            }
        }
    }
    __syncthreads();

    // ---- stage 2: out = T @ W2 + b2 ----
    f32x4 acc2[4];
#pragma unroll
    for (int wr = 0; wr < 4; ++wr) acc2[wr] = zf;

#pragma unroll
    for (int kc = 0; kc < 4; ++kc) {
        bf16x8 bh = as_bf16x8(*(const uint4*)(W2hi + ((size_t)(kc * 8 + cb) * 64 + l) * 8));
        bf16x8 bl = as_bf16x8(*(const uint4*)(W2lo + ((size_t)(kc * 8 + cb) * 64 + l) * 8));
#pragma unroll
        for (int wr = 0; wr < 4; ++wr) {
            bf16x8 a_h = as_bf16x8(*(const uint4*)(ahi + ((size_t)(wr * 4 + kc) * 64 + l) * 8));
            bf16x8 a_l = as_bf16x8(*(const uint4*)(alo + ((size_t)(wr * 4 + kc) * 64 + l) * 8));
            acc2[wr] = __builtin_amdgcn_mfma_f32_16x16x32_bf16(a_h, bh, acc2[wr], 0, 0, 0);
            acc2[wr] = __builtin_amdgcn_mfma_f32_16x16x32_bf16(a_l, bh, acc2[wr], 0, 0, 0);
            acc2[wr] = __builtin_amdgcn_mfma_f32_16x16x32_bf16(a_h, bl, acc2[wr], 0, 0, 0);
        }
    }
    __syncthreads();   // stage-2 fragment reads complete; reuse afrag as fp32 staging

    // ---- epilogue: stage Hpre tile in LDS, coalesced row stores, BN partial stats ----
    float* sf = (float*)afrag;       // 8192 floats = 64 rows x 128
    {
        float b2c = B2[cb * 16 + (l & 15)];
        int col = cb * 16 + (l & 15);
        float s0 = 0.f, q0 = 0.f;
#pragma unroll
        for (int wr = 0; wr < 4; ++wr) {
#pragma unroll
            for (int r = 0; r < 4; ++r) {
                int lrow = wr * 16 + (l >> 4) * 4 + r;
                float o = acc2[wr][r] + b2c;
                sf[lrow * 128 + col] = o;
                if (row0 + lrow < N_NODES) { s0 += o; q0 += o * o; }
            }
        }
        red[w * 64 + l] = s0;
        red[512 + w * 64 + l] = q0;
    }
    __syncthreads();
#pragma unroll
    for (int it = 0; it < 4; ++it) {
        int fidx = tid + it * 512;           // float4 index
        int lrow = fidx >> 5, c4 = (fidx & 31) * 4;
        if (row0 + lrow < N_NODES)
            *(float4*)(Hpre + (size_t)(row0 + lrow) * 128 + c4) = *(float4*)(sf + lrow * 128 + c4);
    }
    if (tid < 128) {
        int b = (tid >> 4) * 64 + (tid & 15);
        float ss = red[b] + red[b + 16] + red[b + 32] + red[b + 48];
        float qq = red[512 + b] + red[512 + b + 16] + red[512 + b + 32] + red[512 + b + 48];
        atomicAdd(&stats[tid], ss);
        atomicAdd(&stats[128 + tid], qq);
    }
}

// ---------------- BN normalize + relu (+fp16 residual), writes fp16 h ----------------
__global__ void k_bn(const float* __restrict__ Hpre, const float* __restrict__ stats,
                     const float* __restrict__ gamma, const float* __restrict__ beta,
                     const __half* __restrict__ hprev, __half* __restrict__ hout) {
    int idx = blockIdx.x * 256 + threadIdx.x;   // 8-channel group index into [N,128]
    const float invN = 1.f / (float)N_NODES;
    int cg = (idx & 15) * 8;
    const float* hp = Hpre + (size_t)idx * 8;
    float4 v0 = *(const float4*)(hp);
    float4 v1 = *(const float4*)(hp + 4);
    float4 s0a = *(const float4*)(stats + cg);
    float4 s0b = *(const float4*)(stats + cg + 4);
    float4 s1a = *(const float4*)(stats + 128 + cg);
    float4 s1b = *(const float4*)(stats + 128 + cg + 4);
    float4 ga = *(const float4*)(gamma + cg);
    float4 gb = *(const float4*)(gamma + cg + 4);
    float4 ba = *(const float4*)(beta + cg);
    float4 bb = *(const float4*)(beta + cg + 4);
    float vv[8] = {v0.x, v0.y, v0.z, v0.w, v1.x, v1.y, v1.z, v1.w};
    float sm[8] = {s0a.x, s0a.y, s0a.z, s0a.w, s0b.x, s0b.y, s0b.z, s0b.w};
    float sq[8] = {s1a.x, s1a.y, s1a.z, s1a.w, s1b.x, s1b.y, s1b.z, s1b.w};
    float gg[8] = {ga.x, ga.y, ga.z, ga.w, gb.x, gb.y, gb.z, gb.w};
    float be[8] = {ba.x, ba.y, ba.z, ba.w, bb.x, bb.y, bb.z, bb.w};
    float o[8];
#pragma unroll
    for (int j = 0; j < 8; ++j) {
        float mu = sm[j] * invN, var = sq[j] * invN - mu * mu;
        o[j] = fmaxf((vv[j] - mu) * rsqrtf(var + BN_EPS) * gg[j] + be[j], 0.f);
    }
    if (hprev) {
        uint4 pv = *(const uint4*)(hprev + (size_t)idx * 8);
        float2 r0 = __half22float2(__builtin_bit_cast(__half2, pv.x));
        float2 r1 = __half22float2(__builtin_bit_cast(__half2, pv.y));
        float2 r2 = __half22float2(__builtin_bit_cast(__half2, pv.z));
        float2 r3 = __half22float2(__builtin_bit_cast(__half2, pv.w));
        o[0] += r0.x; o[1] += r0.y; o[2] += r1.x; o[3] += r1.y;
        o[4] += r2.x; o[5] += r2.y; o[6] += r3.x; o[7] += r3.y;
    }
    uint4 st;
    st.x = __builtin_bit_cast(unsigned int, __floats2half2_rn(o[0], o[1]));
    st.y = __builtin_bit_cast(unsigned int, __floats2half2_rn(o[2], o[3]));
    st.z = __builtin_bit_cast(unsigned int, __floats2half2_rn(o[4], o[5]));
    st.w = __builtin_bit_cast(unsigned int, __floats2half2_rn(o[6], o[7]));
    *(uint4*)(hout + (size_t)idx * 8) = st;
}

// ---------------- graph boundaries (batch is sorted) ----------------
__global__ void k_bounds(const int* __restrict__ batch, int* __restrict__ gstart,
                         int* __restrict__ gend) {
    int r = blockIdx.x * 256 + threadIdx.x;
    if (r >= N_NODES) return;
    int b = batch[r];
    if (r == 0 || batch[r - 1] != b) gstart[b] = r;
    if (r == N_NODES - 1 || batch[r + 1] != b) gend[b] = r + 1;
}

// ---------------- mean pool per graph (wave per graph, fp16 input) ----------------
__global__ void k_pool(const __half* __restrict__ hh, const int* __restrict__ gstart,
                       const int* __restrict__ gend, float* __restrict__ pooled) {
    int wave = (blockIdx.x * blockDim.x + threadIdx.x) >> 6;
    int lane = threadIdx.x & 63;
    if (wave >= N_GRAPHS) return;
    int g = wave;
    int c = lane * 2;
    int a = gstart[g], b = gend[g];
    float ax = 0.f, ay = 0.f;
    for (int r = a; r < b; ++r) {
        __half2 v = *(const __half2*)(hh + (size_t)r * HID + c);
        float2 f = __half22float2(v);
        ax += f.x;
        ay += f.y;
    }
    float d = fmaxf((float)(b - a), 1.f);
    float2 o;
    o.x = ax / d;
    o.y = ay / d;
    *(float2*)(pooled + (size_t)g * HID + c) = o;
}

// ---------------- head MLP ----------------
__global__ void k_head(const float* __restrict__ pooled, const float* __restrict__ hw1,
                       const float* __restrict__ hb1, const float* __restrict__ hw2,
                       const float* __restrict__ hb2, const float* __restrict__ hw3,
                       const float* __restrict__ hb3, float* __restrict__ out) {
    __shared__ float ps[2][128];
    __shared__ float t1s[2][128];
    __shared__ float red[256];
    int tid = threadIdx.x;
    int rr = tid >> 7, c = tid & 127;
    int row = blockIdx.x * 2 + rr;
    ps[rr][c] = pooled[(size_t)row * 128 + c];
    __syncthreads();
    float a = hb1[c];
    for (int k = 0; k < 128; ++k) a = fmaf(ps[rr][k], hw1[k * 128 + c], a);
    t1s[rr][c] = fmaxf(a, 0.f);
    __syncthreads();
    float b = hb2[c];
    for (int k = 0; k < 128; ++k) b = fmaf(t1s[rr][k], hw2[k * 128 + c], b);
    b = fmaxf(b, 0.f);
    red[tid] = b * hw3[c];
    for (int s = 64; s > 0; s >>= 1) {
        __syncthreads();
        if (c < s) red[tid] += red[tid + s];
    }
    __syncthreads();
    if (c == 0) out[row] = red[tid] + hb3[0];
}

// ---------------- launch ----------------
extern "C" void kernel_launch(void* const* d_in, const int* in_sizes, int n_in,
                              void* d_out, int out_size, void* d_ws, size_t ws_size,
                              hipStream_t stream) {
    const float* x = (const float*)d_in[0];
    const float* edge_attr = (const float*)d_in[1];
    const float* e_w0 = (const float*)d_in[2];
    const float* e_b0 = (const float*)d_in[3];
    const float* w1_0 = (const float*)d_in[4];
    const float* b1_0 = (const float*)d_in[5];
    const float* w2_0 = (const float*)d_in[6];
    const float* b2_0 = (const float*)d_in[7];
    const float* gamma0 = (const float*)d_in[8];
    const float* beta0 = (const float*)d_in[9];
    const float* eps0 = (const float*)d_in[10];
    const float* e_w = (const float*)d_in[11];
    const float* e_b = (const float*)d_in[12];
    const float* w1 = (const float*)d_in[13];
    const float* b1 = (const float*)d_in[14];
    const float* w2 = (const float*)d_in[15];
    const float* b2 = (const float*)d_in[16];
    const float* gamma = (const float*)d_in[17];
    const float* beta = (const float*)d_in[18];
    const float* eps_r = (const float*)d_in[19];
    const float* hw1 = (const float*)d_in[20];
    const float* hb1 = (const float*)d_in[21];
    const float* hw2 = (const float*)d_in[22];
    const float* hb2 = (const float*)d_in[23];
    const float* hw3 = (const float*)d_in[24];
    const float* hb3 = (const float*)d_in[25];
    const int* edge_index = (const int*)d_in[26];
    const int* batch = (const int*)d_in[27];
    float* out = (float*)d_out;

    // workspace layout (all offsets in floats, %4==0 -> 16B aligned)
    float* wsf = (float*)d_ws;
    size_t off = 0;
    float* ZB = wsf + off;     off += (size_t)N_NODES * HID;       // Hpre
    float* pooled = wsf + off; off += (size_t)N_GRAPHS * HID;
    float* stats = wsf + off;  off += 5 * 2 * HID;
    __half* hhA = (__half*)(wsf + off); off += (size_t)N_NODES * HID / 2;  // fp16 h (buf A)
    __half* hhB = (__half*)(wsf + off); off += (size_t)N_NODES * HID / 2;  // fp16 h (buf B)
    int* ib = (int*)(wsf + off);
    uint4* csr_pack = (uint4*)ib;                 // 16B-aligned
    size_t io = 4 * (size_t)N_EDGES;
    int* deg = ib + io;      io += N_NODES;
    int* rowstart = ib + io; io += N_NODES + 4;
    int* cur = ib + io;      io += N_NODES;
    int* gstart = ib + io;   io += N_GRAPHS;
    int* gend = ib + io;     io += N_GRAPHS;
    int* bsum = ib + io;     io += 512;
    int* boff = ib + io;     io += 512;
    unsigned short* Whi = (unsigned short*)(ib + io);          // 10 slots * 16384 ushorts
    unsigned short* Wlo = Whi + 10 * WSLOT;

    const int EB = (N_EDGES + 255) / 256;        // 2344
    const int NB = (N_NODES + 255) / 256;        // 391
    const int BNB = (N_NODES * HID / 8) / 256;   // 6250

    // zero control buffers + pack weights (ws is poisoned before every call)
    k_zero<<<NB, 256, 0, stream>>>(deg, gstart, gend, stats);
    k_pack<<<320, 64, 0, stream>>>(w1_0, w2_0, w1, w2, Whi, Wlo);

    // CSR build
    k_deg<<<EB, 256, 0, stream>>>(edge_index, deg);
    k_scan_a<<<NBLK, SCAN_BS, 0, stream>>>(deg, rowstart, bsum);
    k_scan_b<<<1, 512, 0, stream>>>(bsum, boff);
    k_scan_c<<<NB, 256, 0, stream>>>(rowstart, boff, cur);
    k_fill<<<EB, 256, 0, stream>>>(edge_index, edge_attr, cur, csr_pack);

    // layer 0 (fused agg + MLP)
    k_fused<IN_DIM><<<FB, 512, 0, stream>>>(
        x, (const __half*)nullptr, rowstart, csr_pack, e_w0, e_b0, eps0, 0,
        Whi + 0 * WSLOT, Wlo + 0 * WSLOT, Whi + 1 * WSLOT, Wlo + 1 * WSLOT,
        b1_0, b2_0, ZB, stats);
    k_bn<<<BNB, 256, 0, stream>>>(ZB, stats, gamma0, beta0, (const __half*)nullptr, hhA);

    // layers 1..4 (fp16 node state, double-buffered)
    __half* hcur = hhA;
    __half* hnxt = hhB;
    for (int i = 0; i < NREST; ++i) {
        k_fused<HID><<<FB, 512, 0, stream>>>(
            (const float*)nullptr, hcur, rowstart, csr_pack,
            e_w + (size_t)i * 3 * HID, e_b + (size_t)i * HID, eps_r, i,
            Whi + (size_t)(2 + i) * WSLOT, Wlo + (size_t)(2 + i) * WSLOT,
            Whi + (size_t)(6 + i) * WSLOT, Wlo + (size_t)(6 + i) * WSLOT,
            b1 + (size_t)i * HID, b2 + (size_t)i * HID, ZB,
            stats + (size_t)(i + 1) * 2 * HID);
        k_bn<<<BNB, 256, 0, stream>>>(ZB, stats + (size_t)(i + 1) * 2 * HID,
                                      gamma + (size_t)i * HID, beta + (size_t)i * HID,
                                      hcur, hnxt);
        __half* t = hcur; hcur = hnxt; hnxt = t;
    }

    // pooling + head
    k_bounds<<<NB, 256, 0, stream>>>(batch, gstart, gend);
    k_pool<<<(N_GRAPHS * 64) / 256, 256, 0, stream>>>(hcur, gstart, gend, pooled);
    k_head<<<N_GRAPHS / 2, 256, 0, stream>>>(pooled, hw1, hb1, hw2, hb2, hw3, hb3, out);
}